// Round 2
// baseline (237.231 us; speedup 1.0000x reference)
//
#include <hip/hip_runtime.h>
#include <hip/hip_fp16.h>

#define NN 4096
constexpr int TPB = 256;
constexpr int CPB = 1024;                   // columns per block (256 thr x 4)
constexpr int NSTRIP = NN / CPB;            // 4 column strips
constexpr int RPB = 32;                     // rows per block
constexpr int NROWG = NN / RPB;             // 128 row groups
constexpr int NRSLOT = NSTRIP * (TPB / 64); // 16 row-partial slots

typedef float    f32x4 __attribute__((ext_vector_type(4)));
typedef _Float16 f16x4 __attribute__((ext_vector_type(4)));

__device__ __forceinline__ float sigmoidf_(float x) {
    return 1.0f / (1.0f + __expf(-x));
}

__global__ void init_s_kernel(const float2* __restrict__ bs, float* __restrict__ s1) {
    int x = blockIdx.x * blockDim.x + threadIdx.x;
    float2 v = bs[x];
    s1[x] = sigmoidf_(v.y - v.x);
}

// Fused diff + step-1 (w=0): read base_f once, write fp16 d, emit partials.
template <int WRITE_DF>
__global__ void pass1_kernel(const f32x4* __restrict__ bf, f16x4* __restrict__ df,
                             const float* __restrict__ s1c,
                             float* __restrict__ rowpart, float* __restrict__ colpart) {
    const int t = threadIdx.x;
    const int strip = blockIdx.x & (NSTRIP - 1);
    const int rg = blockIdx.x / NSTRIP;
    const int j0 = strip * CPB + t * 4;

    float s0cv[4];
#pragma unroll
    for (int k = 0; k < 4; ++k) s0cv[k] = 1.0f - s1c[j0 + k];
    float colacc[4] = {0.f, 0.f, 0.f, 0.f};
    const int i0 = rg * RPB;

    for (int r = 0; r < RPB; ++r) {
        const int i = i0 + r;
        const float s1ci = s1c[i];
        const size_t u = ((size_t)i * NN + j0) >> 1;  // f32x4 index
        f32x4 a = __builtin_nontemporal_load(bf + u);
        f32x4 b = __builtin_nontemporal_load(bf + u + 1);
        float dd[4] = {a.y - a.x, a.w - a.z, b.y - b.x, b.w - b.z};
        if (WRITE_DF) {
            f16x4 h;
            h.x = (_Float16)dd[0]; h.y = (_Float16)dd[1];
            h.z = (_Float16)dd[2]; h.w = (_Float16)dd[3];
            df[((size_t)i * NN + j0) >> 2] = h;
        }
        float rowp = 0.f;
#pragma unroll
        for (int k = 0; k < 4; ++k) {
            float f1 = sigmoidf_(dd[k]);
            colacc[k] += s1ci * f1;
            rowp += f1 * s0cv[k];
        }
#pragma unroll
        for (int off = 32; off > 0; off >>= 1) rowp += __shfl_down(rowp, off);
        if ((t & 63) == 0)
            rowpart[(size_t)(strip * (TPB / 64) + (t >> 6)) * NN + i] = rowp;
    }
    *reinterpret_cast<f32x4*>(colpart + (size_t)rg * NN + j0) =
        f32x4{colacc[0], colacc[1], colacc[2], colacc[3]};
}

// Steps 2..4: MODE 0 reads fp16 df; MODE 1 reads base_f directly (fallback).
template <int MODE>
__global__ void step_kernel(const void* __restrict__ src,
                            const float* __restrict__ s1c,
                            const float* __restrict__ s1p,
                            const float* __restrict__ wptr,
                            float* __restrict__ rowpart, float* __restrict__ colpart) {
    const int t = threadIdx.x;
    const int strip = blockIdx.x & (NSTRIP - 1);
    const int rg = blockIdx.x / NSTRIP;
    const int j0 = strip * CPB + t * 4;
    const float w = wptr[0];

    float s0cv[4], ws0p[4];
#pragma unroll
    for (int k = 0; k < 4; ++k) {
        s0cv[k] = 1.0f - s1c[j0 + k];
        ws0p[k] = w * (1.0f - s1p[j0 + k]);
    }
    float colacc[4] = {0.f, 0.f, 0.f, 0.f};
    const int i0 = rg * RPB;

    for (int r = 0; r < RPB; ++r) {
        const int i = i0 + r;
        const float s1ci = s1c[i];
        const float s1pi = s1p[i];
        float dd[4];
        if (MODE == 0) {
            f16x4 h = reinterpret_cast<const f16x4*>(src)[((size_t)i * NN + j0) >> 2];
            dd[0] = (float)h.x; dd[1] = (float)h.y;
            dd[2] = (float)h.z; dd[3] = (float)h.w;
        } else {
            const f32x4* p = reinterpret_cast<const f32x4*>(src) + (((size_t)i * NN + j0) >> 1);
            f32x4 a = p[0], b = p[1];
            dd[0] = a.y - a.x; dd[1] = a.w - a.z;
            dd[2] = b.y - b.x; dd[3] = b.w - b.z;
        }
        float rowp = 0.f;
#pragma unroll
        for (int k = 0; k < 4; ++k) {
            float f1 = sigmoidf_(dd[k] - s1pi * ws0p[k]);
            colacc[k] += s1ci * f1;
            rowp += f1 * s0cv[k];
        }
#pragma unroll
        for (int off = 32; off > 0; off >>= 1) rowp += __shfl_down(rowp, off);
        if ((t & 63) == 0)
            rowpart[(size_t)(strip * (TPB / 64) + (t >> 6)) * NN + i] = rowp;
    }
    *reinterpret_cast<f32x4*>(colpart + (size_t)rg * NN + j0) =
        f32x4{colacc[0], colacc[1], colacc[2], colacc[3]};
}

// Fused step-5 + final out_f write. s1c = sigma^5 (msg + weights), s1p = sigma^4 (f1 arg).
__global__ void pass5_kernel(const f32x4* __restrict__ bf, f32x4* __restrict__ of,
                             const float* __restrict__ s1c,
                             const float* __restrict__ s1p,
                             const float* __restrict__ wptr,
                             float* __restrict__ rowpart, float* __restrict__ colpart) {
    const int t = threadIdx.x;
    const int strip = blockIdx.x & (NSTRIP - 1);
    const int rg = blockIdx.x / NSTRIP;
    const int j0 = strip * CPB + t * 4;
    const float w = wptr[0];

    float s0cv[4], ws0p[4];
#pragma unroll
    for (int k = 0; k < 4; ++k) {
        s0cv[k] = 1.0f - s1c[j0 + k];
        ws0p[k] = w * (1.0f - s1p[j0 + k]);
    }
    float colacc[4] = {0.f, 0.f, 0.f, 0.f};
    const int i0 = rg * RPB;

    for (int r = 0; r < RPB; ++r) {
        const int i = i0 + r;
        const float s1ci = s1c[i];
        const float s1pi = s1p[i];
        const size_t u = ((size_t)i * NN + j0) >> 1;
        f32x4 a = __builtin_nontemporal_load(bf + u);
        f32x4 b = __builtin_nontemporal_load(bf + u + 1);
        float dd[4] = {a.y - a.x, a.w - a.z, b.y - b.x, b.w - b.z};

        const float wi = w * s1ci;
        f32x4 oa = {a.x + wi * s0cv[0], a.y, a.z + wi * s0cv[1], a.w};
        f32x4 ob = {b.x + wi * s0cv[2], b.y, b.z + wi * s0cv[3], b.w};
        __builtin_nontemporal_store(oa, of + u);
        __builtin_nontemporal_store(ob, of + u + 1);

        float rowp = 0.f;
#pragma unroll
        for (int k = 0; k < 4; ++k) {
            float f1 = sigmoidf_(dd[k] - s1pi * ws0p[k]);
            colacc[k] += s1ci * f1;
            rowp += f1 * s0cv[k];
        }
#pragma unroll
        for (int off = 32; off > 0; off >>= 1) rowp += __shfl_down(rowp, off);
        if ((t & 63) == 0)
            rowpart[(size_t)(strip * (TPB / 64) + (t >> 6)) * NN + i] = rowp;
    }
    *reinterpret_cast<f32x4*>(colpart + (size_t)rg * NN + j0) =
        f32x4{colacc[0], colacc[1], colacc[2], colacc[3]};
}

// Reduce partials -> new s; optionally write out_s (last step).
__global__ void update_kernel(const float* __restrict__ rowpart,
                              const float* __restrict__ colpart,
                              const float2* __restrict__ bs,
                              const float* __restrict__ wptr,
                              float* __restrict__ s1next,
                              float2* __restrict__ out_s, int writeOut) {
    int x = blockIdx.x * blockDim.x + threadIdx.x;
    float m0 = 0.f;
#pragma unroll
    for (int s = 0; s < NRSLOT; ++s) m0 += rowpart[(size_t)s * NN + x];
    float m1 = 0.f;
#pragma unroll 4
    for (int g = 0; g < NROWG; ++g) m1 += colpart[(size_t)g * NN + x];
    float w = wptr[0];
    float2 b = bs[x];
    float c0 = b.x + w * m0;
    float c1 = b.y + w * m1;
    s1next[x] = sigmoidf_(c1 - c0);
    if (writeOut) out_s[x] = make_float2(c0, c1);
}

extern "C" void kernel_launch(void* const* d_in, const int* in_sizes, int n_in,
                              void* d_out, int out_size, void* d_ws,
                              size_t ws_size, hipStream_t stream) {
    const float* base_s = (const float*)d_in[0];  // (N,2)
    const float* base_f = (const float*)d_in[1];  // (N,N,2)
    const float* wptr = (const float*)d_in[2];    // (1,)
    float2* out_s = (float2*)d_out;               // first 2N floats
    f32x4* out_f = (f32x4*)((float*)d_out + 2 * NN);

    char* ws = (char*)d_ws;
    size_t off = 0;
    auto alloc = [&](size_t bytes) {
        void* p = ws + off;
        off = (off + bytes + 255) & ~(size_t)255;
        return p;
    };
    float* sA = (float*)alloc((size_t)NN * 4);
    float* sB = (float*)alloc((size_t)NN * 4);
    float* rowpart = (float*)alloc((size_t)NRSLOT * NN * 4);
    float* colpart = (float*)alloc((size_t)NROWG * NN * 4);
    f16x4* df = (f16x4*)(ws + off);
    const bool use_df = (ws_size >= off + (size_t)NN * NN * 2);

    const int NB = NSTRIP * NROWG;  // 512 blocks
    const f32x4* bf = (const f32x4*)base_f;

    init_s_kernel<<<NN / 64, 64, 0, stream>>>((const float2*)base_s, sA);  // sigma^1

    if (use_df)
        pass1_kernel<1><<<NB, TPB, 0, stream>>>(bf, df, sA, rowpart, colpart);
    else
        pass1_kernel<0><<<NB, TPB, 0, stream>>>(bf, df, sA, rowpart, colpart);
    update_kernel<<<NN / 64, 64, 0, stream>>>(rowpart, colpart, (const float2*)base_s,
                                              wptr, sB, out_s, 0);  // sigma^2

    float* cur = sB;   // sigma^k
    float* prev = sA;  // sigma^(k-1)
    for (int k = 2; k <= 4; ++k) {
        if (use_df)
            step_kernel<0><<<NB, TPB, 0, stream>>>(df, cur, prev, wptr, rowpart, colpart);
        else
            step_kernel<1><<<NB, TPB, 0, stream>>>(base_f, cur, prev, wptr, rowpart, colpart);
        update_kernel<<<NN / 64, 64, 0, stream>>>(rowpart, colpart, (const float2*)base_s,
                                                  wptr, prev, out_s, 0);  // sigma^(k+1) -> old prev
        float* t = cur; cur = prev; prev = t;
    }
    // now cur = sigma^5, prev = sigma^4
    pass5_kernel<<<NB, TPB, 0, stream>>>(bf, out_f, cur, prev, wptr, rowpart, colpart);
    update_kernel<<<NN / 64, 64, 0, stream>>>(rowpart, colpart, (const float2*)base_s,
                                              wptr, prev, out_s, 1);  // writes out_s
}

// Round 3
// 185.264 us; speedup vs baseline: 1.2805x; 1.2805x over previous
//
#include <hip/hip_runtime.h>
#include <hip/hip_fp16.h>

#define NN 4096
constexpr int TPB = 256;
constexpr int CPB = 1024;                   // columns per block (256 thr x 4)
constexpr int NSTRIP = NN / CPB;            // 4 column strips
constexpr int RPB = 16;                     // rows per block
constexpr int NROWG = NN / RPB;             // 256 row groups
constexpr int NRSLOT = NSTRIP * (TPB / 64); // 16 row-partial slots

typedef float    f32x4 __attribute__((ext_vector_type(4)));
typedef _Float16 f16x4 __attribute__((ext_vector_type(4)));

__device__ __forceinline__ float sigmoidf_(float x) {
    return 1.0f / (1.0f + __expf(-x));
}

__global__ void init_s_kernel(const float2* __restrict__ bs, float* __restrict__ s1) {
    int x = blockIdx.x * blockDim.x + threadIdx.x;
    float2 v = bs[x];
    s1[x] = sigmoidf_(v.y - v.x);
}

// Fused diff + step-1 (w=0): read base_f once (allocating in L3), write fp16 d,
// emit row/col partials.
template <int WRITE_DF>
__global__ void pass1_kernel(const f32x4* __restrict__ bf, f16x4* __restrict__ df,
                             const float* __restrict__ s1c,
                             float* __restrict__ rowpart, float* __restrict__ colpart) {
    const int t = threadIdx.x;
    const int strip = blockIdx.x & (NSTRIP - 1);
    const int rg = blockIdx.x / NSTRIP;
    const int j0 = strip * CPB + t * 4;

    float s0cv[4];
#pragma unroll
    for (int k = 0; k < 4; ++k) s0cv[k] = 1.0f - s1c[j0 + k];
    float colacc[4] = {0.f, 0.f, 0.f, 0.f};
    const int i0 = rg * RPB;

    for (int r = 0; r < RPB; ++r) {
        const int i = i0 + r;
        const float s1ci = s1c[i];
        const size_t u = ((size_t)i * NN + j0) >> 1;  // f32x4 index
        f32x4 a = bf[u];
        f32x4 b = bf[u + 1];
        float dd[4] = {a.y - a.x, a.w - a.z, b.y - b.x, b.w - b.z};
        if (WRITE_DF) {
            f16x4 h;
            h.x = (_Float16)dd[0]; h.y = (_Float16)dd[1];
            h.z = (_Float16)dd[2]; h.w = (_Float16)dd[3];
            df[((size_t)i * NN + j0) >> 2] = h;
        }
        float rowp = 0.f;
#pragma unroll
        for (int k = 0; k < 4; ++k) {
            float f1 = sigmoidf_(dd[k]);
            colacc[k] += s1ci * f1;
            rowp += f1 * s0cv[k];
        }
#pragma unroll
        for (int off = 32; off > 0; off >>= 1) rowp += __shfl_down(rowp, off);
        if ((t & 63) == 0)
            rowpart[(size_t)(strip * (TPB / 64) + (t >> 6)) * NN + i] = rowp;
    }
    *reinterpret_cast<f32x4*>(colpart + (size_t)rg * NN + j0) =
        f32x4{colacc[0], colacc[1], colacc[2], colacc[3]};
}

// Steps 2..4: MODE 0 reads fp16 df (L3-resident); MODE 1 reads base_f (fallback).
template <int MODE>
__global__ void step_kernel(const void* __restrict__ src,
                            const float* __restrict__ s1c,
                            const float* __restrict__ s1p,
                            const float* __restrict__ wptr,
                            float* __restrict__ rowpart, float* __restrict__ colpart) {
    const int t = threadIdx.x;
    const int strip = blockIdx.x & (NSTRIP - 1);
    const int rg = blockIdx.x / NSTRIP;
    const int j0 = strip * CPB + t * 4;
    const float w = wptr[0];

    float s0cv[4], ws0p[4];
#pragma unroll
    for (int k = 0; k < 4; ++k) {
        s0cv[k] = 1.0f - s1c[j0 + k];
        ws0p[k] = w * (1.0f - s1p[j0 + k]);
    }
    float colacc[4] = {0.f, 0.f, 0.f, 0.f};
    const int i0 = rg * RPB;

#pragma unroll 2
    for (int r = 0; r < RPB; ++r) {
        const int i = i0 + r;
        const float s1ci = s1c[i];
        const float s1pi = s1p[i];
        float dd[4];
        if (MODE == 0) {
            f16x4 h = reinterpret_cast<const f16x4*>(src)[((size_t)i * NN + j0) >> 2];
            dd[0] = (float)h.x; dd[1] = (float)h.y;
            dd[2] = (float)h.z; dd[3] = (float)h.w;
        } else {
            const f32x4* p = reinterpret_cast<const f32x4*>(src) + (((size_t)i * NN + j0) >> 1);
            f32x4 a = p[0], b = p[1];
            dd[0] = a.y - a.x; dd[1] = a.w - a.z;
            dd[2] = b.y - b.x; dd[3] = b.w - b.z;
        }
        float rowp = 0.f;
#pragma unroll
        for (int k = 0; k < 4; ++k) {
            float f1 = sigmoidf_(dd[k] - s1pi * ws0p[k]);
            colacc[k] += s1ci * f1;
            rowp += f1 * s0cv[k];
        }
#pragma unroll
        for (int off = 32; off > 0; off >>= 1) rowp += __shfl_down(rowp, off);
        if ((t & 63) == 0)
            rowpart[(size_t)(strip * (TPB / 64) + (t >> 6)) * NN + i] = rowp;
    }
    *reinterpret_cast<f32x4*>(colpart + (size_t)rg * NN + j0) =
        f32x4{colacc[0], colacc[1], colacc[2], colacc[3]};
}

// Fused step-5 + final out_f write. s1c = sigma^5, s1p = sigma^4.
// base_f read (hopefully L3-hit), out_f written nontemporal (don't evict).
__global__ void pass5_kernel(const f32x4* __restrict__ bf, f32x4* __restrict__ of,
                             const float* __restrict__ s1c,
                             const float* __restrict__ s1p,
                             const float* __restrict__ wptr,
                             float* __restrict__ rowpart, float* __restrict__ colpart) {
    const int t = threadIdx.x;
    const int strip = blockIdx.x & (NSTRIP - 1);
    const int rg = blockIdx.x / NSTRIP;
    const int j0 = strip * CPB + t * 4;
    const float w = wptr[0];

    float s0cv[4], ws0p[4];
#pragma unroll
    for (int k = 0; k < 4; ++k) {
        s0cv[k] = 1.0f - s1c[j0 + k];
        ws0p[k] = w * (1.0f - s1p[j0 + k]);
    }
    float colacc[4] = {0.f, 0.f, 0.f, 0.f};
    const int i0 = rg * RPB;

    for (int r = 0; r < RPB; ++r) {
        const int i = i0 + r;
        const float s1ci = s1c[i];
        const float s1pi = s1p[i];
        const size_t u = ((size_t)i * NN + j0) >> 1;
        f32x4 a = bf[u];
        f32x4 b = bf[u + 1];
        float dd[4] = {a.y - a.x, a.w - a.z, b.y - b.x, b.w - b.z};

        const float wi = w * s1ci;
        f32x4 oa = {a.x + wi * s0cv[0], a.y, a.z + wi * s0cv[1], a.w};
        f32x4 ob = {b.x + wi * s0cv[2], b.y, b.z + wi * s0cv[3], b.w};
        __builtin_nontemporal_store(oa, of + u);
        __builtin_nontemporal_store(ob, of + u + 1);

        float rowp = 0.f;
#pragma unroll
        for (int k = 0; k < 4; ++k) {
            float f1 = sigmoidf_(dd[k] - s1pi * ws0p[k]);
            colacc[k] += s1ci * f1;
            rowp += f1 * s0cv[k];
        }
#pragma unroll
        for (int off = 32; off > 0; off >>= 1) rowp += __shfl_down(rowp, off);
        if ((t & 63) == 0)
            rowpart[(size_t)(strip * (TPB / 64) + (t >> 6)) * NN + i] = rowp;
    }
    *reinterpret_cast<f32x4*>(colpart + (size_t)rg * NN + j0) =
        f32x4{colacc[0], colacc[1], colacc[2], colacc[3]};
}

// Parallel partial-reduce -> new s. 64 blocks x 256 thr; wave s sums its
// slice of groups (coalesced across 64 consecutive x), LDS-combine.
__global__ void update_kernel(const float* __restrict__ rowpart,
                              const float* __restrict__ colpart,
                              const float2* __restrict__ bs,
                              const float* __restrict__ wptr,
                              float* __restrict__ s1next,
                              float2* __restrict__ out_s, int writeOut) {
    __shared__ float m0s[4][64];
    __shared__ float m1s[4][64];
    const int xl = threadIdx.x & 63;
    const int sl = threadIdx.x >> 6;
    const int x = blockIdx.x * 64 + xl;

    float m1 = 0.f;
    const int g0 = sl * (NROWG / 4);
#pragma unroll 8
    for (int g = g0; g < g0 + NROWG / 4; ++g) m1 += colpart[(size_t)g * NN + x];
    float m0 = 0.f;
    const int s0 = sl * (NRSLOT / 4);
#pragma unroll
    for (int s = s0; s < s0 + NRSLOT / 4; ++s) m0 += rowpart[(size_t)s * NN + x];
    m0s[sl][xl] = m0;
    m1s[sl][xl] = m1;
    __syncthreads();
    if (sl == 0) {
        m0 = m0s[0][xl] + m0s[1][xl] + m0s[2][xl] + m0s[3][xl];
        m1 = m1s[0][xl] + m1s[1][xl] + m1s[2][xl] + m1s[3][xl];
        float w = wptr[0];
        float2 b = bs[x];
        float c0 = b.x + w * m0;
        float c1 = b.y + w * m1;
        s1next[x] = sigmoidf_(c1 - c0);
        if (writeOut) out_s[x] = make_float2(c0, c1);
    }
}

extern "C" void kernel_launch(void* const* d_in, const int* in_sizes, int n_in,
                              void* d_out, int out_size, void* d_ws,
                              size_t ws_size, hipStream_t stream) {
    const float* base_s = (const float*)d_in[0];  // (N,2)
    const float* base_f = (const float*)d_in[1];  // (N,N,2)
    const float* wptr = (const float*)d_in[2];    // (1,)
    float2* out_s = (float2*)d_out;               // first 2N floats
    f32x4* out_f = (f32x4*)((float*)d_out + 2 * NN);

    char* ws = (char*)d_ws;
    size_t off = 0;
    auto alloc = [&](size_t bytes) {
        void* p = ws + off;
        off = (off + bytes + 255) & ~(size_t)255;
        return p;
    };
    float* sA = (float*)alloc((size_t)NN * 4);
    float* sB = (float*)alloc((size_t)NN * 4);
    float* rowpart = (float*)alloc((size_t)NRSLOT * NN * 4);
    float* colpart = (float*)alloc((size_t)NROWG * NN * 4);
    f16x4* df = (f16x4*)(ws + off);
    const bool use_df = (ws_size >= off + (size_t)NN * NN * 2);

    const int NB = NSTRIP * NROWG;  // 1024 blocks
    const f32x4* bf = (const f32x4*)base_f;

    init_s_kernel<<<NN / 256, 256, 0, stream>>>((const float2*)base_s, sA);  // sigma^1

    if (use_df)
        pass1_kernel<1><<<NB, TPB, 0, stream>>>(bf, df, sA, rowpart, colpart);
    else
        pass1_kernel<0><<<NB, TPB, 0, stream>>>(bf, df, sA, rowpart, colpart);
    update_kernel<<<NN / 64, 256, 0, stream>>>(rowpart, colpart, (const float2*)base_s,
                                               wptr, sB, out_s, 0);  // sigma^2

    float* cur = sB;   // sigma^k
    float* prev = sA;  // sigma^(k-1)
    for (int k = 2; k <= 4; ++k) {
        if (use_df)
            step_kernel<0><<<NB, TPB, 0, stream>>>(df, cur, prev, wptr, rowpart, colpart);
        else
            step_kernel<1><<<NB, TPB, 0, stream>>>(base_f, cur, prev, wptr, rowpart, colpart);
        update_kernel<<<NN / 64, 256, 0, stream>>>(rowpart, colpart, (const float2*)base_s,
                                                   wptr, prev, out_s, 0);  // sigma^(k+1)
        float* t = cur; cur = prev; prev = t;
    }
    // cur = sigma^5, prev = sigma^4
    pass5_kernel<<<NB, TPB, 0, stream>>>(bf, out_f, cur, prev, wptr, rowpart, colpart);
    update_kernel<<<NN / 64, 256, 0, stream>>>(rowpart, colpart, (const float2*)base_s,
                                               wptr, prev, out_s, 1);  // writes out_s
}